// Round 10
// baseline (234.060 us; speedup 1.0000x reference)
//
#include <hip/hip_runtime.h>
#include <math.h>

// QURNN cell, MI355X gfx950, f32 I/O. B=4096, D_IN=D_H=1024.
//
// Round 10: corrected 256x256 8-phase GEMM (two-barrier fine interleave per
// m201 template): per phase {ds_read frags + issue 1 staging group} BEFORE
// the opening barrier (latency hides under barrier wait), MFMA cluster
// between barriers, counted vmcnt(4) before the closing barrier of phases
// 2 and 4 only (never 0 mid-loop). b-frags reused across C-half phases.
// Trailing barrier + syncthreads between Tr/Ei back-to-back calls.
// All gemm5 outputs f16 now (ut/ratio f16: -32MB traffic, DELTA 4e-3).
// eh/convert/cell/fixup otherwise unchanged from round 8 (proven).

typedef __attribute__((ext_vector_type(4))) float f32x4;
typedef __attribute__((ext_vector_type(8))) _Float16 half8;
typedef __attribute__((ext_vector_type(4))) _Float16 half4;

#define NEL (4096 * 1024)
#define DELTA 4.0e-3f
#define COLCAP 512

__device__ __forceinline__ float sigm(float x) { return 1.0f / (1.0f + expf(-x)); }

__device__ __forceinline__ void gload16(const void* g, void* l) {
  __builtin_amdgcn_global_load_lds(
      (const __attribute__((address_space(1))) void*)g,
      (__attribute__((address_space(3))) void*)l, 16, 0, 0);
}

#define SB() __builtin_amdgcn_sched_barrier(0)

// ================= 256x256 8-phase GEMM =================
// OP: 1 = tanh->f16, 2 = sigmoid->f16.
// LDS buf b at b*32768: A-k0 | B-k0 | A-k1 | B-k1 (8192 f16 each; 256rx32k).
// Slot p = (row>>3)*32 | (row&7) | chunk*8 ; linear gload dest, permuted
// global source, matching read perm -> 2-way banks (free), 0 conflicts (r9).
template <int OP, int NT>
__device__ void gemm256(_Float16* sm, const int brow, const int bcol,
                        const _Float16* A1, const _Float16* A2,
                        const _Float16* W, const float* bias, _Float16* outH)
{
  const int tid = threadIdx.x;
  const int lane = tid & 63, w = tid >> 6;
  const int wr = w >> 2, wc = w & 3;            // 2x4 waves, 128x64 C each
  const int lr = lane & 15, lq = lane >> 4;

  const int s0 = tid, s1 = tid + 512;
  const int r0 = ((s0 >> 5) << 3) | (s0 & 7), c0 = (s0 >> 3) & 3;
  const int r1 = ((s1 >> 5) << 3) | (s1 & 7), c1 = (s1 >> 3) & 3;

  int pA[8], pB[4];
#pragma unroll
  for (int m = 0; m < 8; ++m) {
    const int R = wr * 128 + m * 16 + lr;
    pA[m] = ((((R >> 3) << 5) | (R & 7)) | (lq << 3)) * 8;
  }
#pragma unroll
  for (int n = 0; n < 4; ++n) {
    const int R = wc * 64 + n * 16 + lr;
    pB[n] = ((((R >> 3) << 5) | (R & 7)) | (lq << 3)) * 8;
  }

  auto issue = [&](int tt, int g, int bfx) {
    _Float16* dst = sm + bfx * 32768 + g * 8192;
    const int kh = g >> 1;
    if ((g & 1) == 0) {
      const _Float16* Ap = (NT == 32 && tt >= 16) ? A2 : A1;
      const int kk = ((NT == 32) ? (tt & 15) : tt) * 64 + kh * 32;
      gload16(Ap + (size_t)(brow + r0) * 1024 + kk + c0 * 8, dst + s0 * 8);
      gload16(Ap + (size_t)(brow + r1) * 1024 + kk + c1 * 8, dst + s1 * 8);
    } else {
      const int kk = tt * 64 + kh * 32;
      gload16(W + (size_t)(bcol + r0) * (NT * 64) + kk + c0 * 8, dst + s0 * 8);
      gload16(W + (size_t)(bcol + r1) * (NT * 64) + kk + c1 * 8, dst + s1 * 8);
    }
  };

  f32x4 acc[8][4] = {};

  asm volatile("s_waitcnt vmcnt(0)" ::: "memory");
  SB();
  issue(0, 0, 0); issue(0, 1, 0); issue(0, 2, 0); issue(0, 3, 0);
  asm volatile("s_waitcnt vmcnt(4)" ::: "memory");
  SB();
  __builtin_amdgcn_s_barrier();
  SB();

  for (int t = 0; t < NT; ++t) {
    const int bf = t & 1, nx = bf ^ 1;
    const bool more = (t + 1) < NT;
    const _Float16* Ab0 = sm + bf * 32768;
    const _Float16* Bb0 = Ab0 + 8192;
    const _Float16* Ab1 = Ab0 + 16384;
    const _Float16* Bb1 = Ab0 + 24576;
    half8 a_[4], b_[4];

    // ---- P1: C-rows 0-3 x k-half 0 (read b k0 + a rows0-3 k0)
#pragma unroll
    for (int n = 0; n < 4; ++n) b_[n] = *(const half8*)(Bb0 + pB[n]);
#pragma unroll
    for (int m = 0; m < 4; ++m) a_[m] = *(const half8*)(Ab0 + pA[m]);
    if (more) issue(t + 1, 0, nx);
    SB(); __builtin_amdgcn_s_barrier(); SB();
    __builtin_amdgcn_s_setprio(1);
#pragma unroll
    for (int m = 0; m < 4; ++m)
#pragma unroll
      for (int n = 0; n < 4; ++n)
        acc[m][n] = __builtin_amdgcn_mfma_f32_16x16x32_f16(a_[m], b_[n], acc[m][n], 0, 0, 0);
    __builtin_amdgcn_s_setprio(0);
    SB(); __builtin_amdgcn_s_barrier(); SB();

    // ---- P2: C-rows 4-7 x k0 (b reused)
#pragma unroll
    for (int m = 0; m < 4; ++m) a_[m] = *(const half8*)(Ab0 + pA[4 + m]);
    if (more) issue(t + 1, 1, nx);
    SB(); __builtin_amdgcn_s_barrier(); SB();
    __builtin_amdgcn_s_setprio(1);
#pragma unroll
    for (int m = 0; m < 4; ++m)
#pragma unroll
      for (int n = 0; n < 4; ++n)
        acc[4 + m][n] = __builtin_amdgcn_mfma_f32_16x16x32_f16(a_[m], b_[n], acc[4 + m][n], 0, 0, 0);
    __builtin_amdgcn_s_setprio(0);
    if (more) { asm volatile("s_waitcnt vmcnt(4)" ::: "memory"); }
    else      { asm volatile("s_waitcnt vmcnt(0)" ::: "memory"); }
    SB(); __builtin_amdgcn_s_barrier(); SB();

    // ---- P3: C-rows 0-3 x k-half 1 (read b k1 + a rows0-3 k1)
#pragma unroll
    for (int n = 0; n < 4; ++n) b_[n] = *(const half8*)(Bb1 + pB[n]);
#pragma unroll
    for (int m = 0; m < 4; ++m) a_[m] = *(const half8*)(Ab1 + pA[m]);
    if (more) issue(t + 1, 2, nx);
    SB(); __builtin_amdgcn_s_barrier(); SB();
    __builtin_amdgcn_s_setprio(1);
#pragma unroll
    for (int m = 0; m < 4; ++m)
#pragma unroll
      for (int n = 0; n < 4; ++n)
        acc[m][n] = __builtin_amdgcn_mfma_f32_16x16x32_f16(a_[m], b_[n], acc[m][n], 0, 0, 0);
    __builtin_amdgcn_s_setprio(0);
    SB(); __builtin_amdgcn_s_barrier(); SB();

    // ---- P4: C-rows 4-7 x k1
#pragma unroll
    for (int m = 0; m < 4; ++m) a_[m] = *(const half8*)(Ab1 + pA[4 + m]);
    if (more) issue(t + 1, 3, nx);
    SB(); __builtin_amdgcn_s_barrier(); SB();
    __builtin_amdgcn_s_setprio(1);
#pragma unroll
    for (int m = 0; m < 4; ++m)
#pragma unroll
      for (int n = 0; n < 4; ++n)
        acc[4 + m][n] = __builtin_amdgcn_mfma_f32_16x16x32_f16(a_[m], b_[n], acc[4 + m][n], 0, 0, 0);
    __builtin_amdgcn_s_setprio(0);
    if (more) { asm volatile("s_waitcnt vmcnt(4)" ::: "memory"); }
    SB(); __builtin_amdgcn_s_barrier(); SB();
  }

  float bv[4];
#pragma unroll
  for (int n = 0; n < 4; ++n) bv[n] = bias[bcol + wc * 64 + n * 16 + lr];
#pragma unroll
  for (int m = 0; m < 8; ++m)
#pragma unroll
    for (int n = 0; n < 4; ++n) {
      const int col = bcol + wc * 64 + n * 16 + lr;
#pragma unroll
      for (int j = 0; j < 4; ++j) {
        const int row = brow + wr * 128 + m * 16 + lq * 4 + j;
        const size_t idx = (size_t)row * 1024 + col;
        const float v = acc[m][n][j] + bv[n];
        outH[idx] = (_Float16)(OP == 1 ? tanhf(v) : sigm(v));
      }
    }
}

// 256 blocks: 0-63 Wt, 64-127 Wa, 128-191 Hw, 192-255 {Tr then Ei}.
__global__ __launch_bounds__(512, 2)
void qurnn_gemm256(const _Float16* inpH, const _Float16* hcH,
                   const _Float16* WtH, const float* Wt_b,
                   const _Float16* WaH, const float* Wa_b,
                   const _Float16* HwH, const float* Hw_b,
                   const _Float16* TrH, const float* Tr_b,
                   const _Float16* EiH, const float* Ei_b,
                   _Float16* ws_ut, _Float16* ws_ab, _Float16* ws_hw,
                   _Float16* ws_ra, _Float16* ws_ei)
{
  __shared__ __align__(16) _Float16 sm[65536];   // 128KB, 2x64KB dbuf
  const int b = blockIdx.x;
  const int tile = (b < 192) ? (b & 63) : (b - 192);
  const int brow = (tile & 15) * 256;
  const int bcol = (tile >> 4) * 256;
  if (b < 64) {
    gemm256<1, 32>(sm, brow, bcol, inpH, hcH, WtH, Wt_b, ws_ut);
  } else if (b < 128) {
    gemm256<2, 32>(sm, brow, bcol, inpH, hcH, WaH, Wa_b, ws_ab);
  } else if (b < 192) {
    gemm256<2, 32>(sm, brow, bcol, inpH, hcH, HwH, Hw_b, ws_hw);
  } else {
    gemm256<2, 16>(sm, brow, bcol, inpH, nullptr, TrH, Tr_b, ws_ra);
    __syncthreads();
    gemm256<2, 16>(sm, brow, bcol, inpH, nullptr, EiH, Ei_b, ws_ei);
  }
}

// ================= 128x128 GEMM (eh only, proven r6-r8) =================
__global__ __launch_bounds__(256, 3)
void qurnn_eh(const _Float16* inpH, const _Float16* hup,
              const _Float16* EhH, const float* Eh_b,
              const _Float16* hw, const float* hcur, float* out_h)
{
  __shared__ __align__(16) _Float16 sm[2 * 8192];
  _Float16* As = sm;
  _Float16* Bs = sm + 8192;
  const int brow = (blockIdx.x & 31) * 128;
  const int bcol = (blockIdx.x >> 5) * 128;
  const int tid = threadIdx.x;
  const int lane = tid & 63;
  const int w = tid >> 6;
  const int wr = w >> 1, wc = w & 1;
  const int lr = lane & 15, lq = lane >> 4;

  f32x4 acc[4][4] = {};

  for (int k0 = 0; k0 < 2048; k0 += 64) {
    const _Float16* Ah = (k0 < 1024) ? inpH : hup;
    const int kk = k0 & 1023;
    __syncthreads();
#pragma unroll
    for (int i = 0; i < 4; ++i) {
      const int c_lin = i * 256 + tid;
      const int row = c_lin >> 3;
      const int c = c_lin & 7;
      const int src = (c ^ (row & 7)) * 8;
      gload16(Ah + (size_t)(brow + row) * 1024 + kk + src, &As[row * 64 + c * 8]);
      gload16(EhH + (size_t)(bcol + row) * 2048 + k0 + src, &Bs[row * 64 + c * 8]);
    }
    __syncthreads();

#pragma unroll
    for (int h = 0; h < 2; ++h) {
      half8 a[4], b[4];
#pragma unroll
      for (int m = 0; m < 4; ++m) {
        const int row = wr * 64 + m * 16 + lr;
        const int ch = (lq + 4 * h) ^ (row & 7);
        a[m] = *(const half8*)&As[row * 64 + ch * 8];
      }
#pragma unroll
      for (int n = 0; n < 4; ++n) {
        const int row = wc * 64 + n * 16 + lr;
        const int ch = (lq + 4 * h) ^ (row & 7);
        b[n] = *(const half8*)&Bs[row * 64 + ch * 8];
      }
#pragma unroll
      for (int m = 0; m < 4; ++m)
#pragma unroll
        for (int n = 0; n < 4; ++n)
          acc[m][n] = __builtin_amdgcn_mfma_f32_16x16x32_f16(a[m], b[n], acc[m][n], 0, 0, 0);
    }
  }

  float bv[4];
#pragma unroll
  for (int n = 0; n < 4; ++n) bv[n] = Eh_b[bcol + wc * 64 + n * 16 + lr];

#pragma unroll
  for (int m = 0; m < 4; ++m)
#pragma unroll
    for (int n = 0; n < 4; ++n) {
      const int col = bcol + wc * 64 + n * 16 + lr;
#pragma unroll
      for (int j = 0; j < 4; ++j) {
        const int rowg = brow + wr * 64 + m * 16 + lq * 4 + j;
        const size_t idx = (size_t)rowg * 1024 + col;
        const float hs = tanhf(acc[m][n][j] + bv[n]);
        const float hwv = (float)hw[idx];
        const float hcv = hcur[idx];
        out_h[idx] = tanhf((1.0f - hwv) * hcv + hwv * hs);
      }
    }
}

__global__ __launch_bounds__(256)
void qurnn_cell(const f32x4* tc, const f32x4* ec, const f32x4* hc,
                const half4* ut, const half4* ra, const half4* ab,
                const half4* ei, f32x4* out_ex, f32x4* out_tm, half4* hup,
                int* colcnt, int* collist)
{
  const int i = blockIdx.x * 256 + threadIdx.x;   // exact: 4096 blocks
  const f32x4 tcv = tc[i], ecv = ec[i], hcv = hc[i];
  const half4 utv = ut[i], rav = ra[i], abv = ab[i], eiv = ei[i];
  f32x4 to, eo; half4 ho;
#pragma unroll
  for (int j = 0; j < 4; ++j) {
    const float t = (float)rav[j] * fmaxf(tcv[j] + (float)utv[j], 0.0f) - 1.0f;
    const bool leap = (t <= 0.0f);
    to[j] = leap ? 0.0f : t;
    eo[j] = (leap ? 0.0f : ecv[j] + (float)eiv[j]) + (float)abv[j];
    ho[j] = (_Float16)(leap ? hcv[j] * ecv[j] : 0.0f);
    if (fabsf(t) < DELTA) {                  // leap uncertain -> col bucket
      const int e = i * 4 + j;
      const int col = e & 1023;
      const int p = atomicAdd(&colcnt[col], 1);
      if (p < COLCAP) collist[col * COLCAP + p] = e >> 10;  // row
    }
  }
  out_tm[i] = to;
  out_ex[i] = eo;
  hup[i] = ho;
}

__global__ __launch_bounds__(256)
void qurnn_fixup(const int* colcnt, const int* collist,
                 const float* inp, const float* hcur,
                 const float* Tr_w, const float* Tr_b,
                 const float* Wt_w, const float* Wt_b,
                 const _Float16* ei, const _Float16* ab,
                 const float* tc, const float* ec,
                 float* out_tm, float* out_ex, _Float16* hup)
{
  const int col = blockIdx.x;                 // 1024 blocks
  const int n_c = min(colcnt[col], COLCAP);
  if (n_c == 0) return;
  __shared__ float wTr[1024];
  __shared__ float wWt[2048];
  const int tid = threadIdx.x;
  for (int k = tid; k < 1024; k += 256) wTr[k] = Tr_w[(size_t)col * 1024 + k];
  for (int k = tid; k < 2048; k += 256) wWt[k] = Wt_w[(size_t)col * 2048 + k];
  __syncthreads();

  const int wid = tid >> 6, lane = tid & 63;
  for (int e = wid; e < n_c; e += 4) {
    const int row = collist[col * COLCAP + e];
    const int idx = row * 1024 + col;
    const f32x4* irow = (const f32x4*)(inp  + (size_t)row * 1024);
    const f32x4* hrow = (const f32x4*)(hcur + (size_t)row * 1024);
    float dTr = 0.0f, dWt = 0.0f;
#pragma unroll
    for (int k = 0; k < 4; ++k) {
      const int q = k * 64 + lane;
      const f32x4 a = irow[q], h = hrow[q];
      const f32x4 w1 = *(const f32x4*)&wTr[q * 4];
      const f32x4 w2 = *(const f32x4*)&wWt[q * 4];
      const f32x4 w3 = *(const f32x4*)&wWt[1024 + q * 4];
#pragma unroll
      for (int j = 0; j < 4; ++j) {
        dTr = fmaf(a[j], w1[j], dTr);
        dWt = fmaf(a[j], w2[j], dWt);
        dWt = fmaf(h[j], w3[j], dWt);
      }
    }
#pragma unroll
    for (int s = 32; s; s >>= 1) {
      dTr += __shfl_xor(dTr, s);
      dWt += __shfl_xor(dWt, s);
    }
    if (lane == 0) {
      const float ratio = sigm(dTr + Tr_b[col]);
      const float utv = tanhf(dWt + Wt_b[col]);
      const float t = ratio * fmaxf(tc[idx] + utv, 0.0f) - 1.0f;
      const bool leap = (t <= 0.0f);
      out_tm[idx] = leap ? 0.0f : t;
      out_ex[idx] = (leap ? 0.0f : ec[idx] + (float)ei[idx]) + (float)ab[idx];
      hup[idx] = (_Float16)(leap ? hcur[idx] * ec[idx] : 0.0f);
    }
  }
}

__global__ __launch_bounds__(256)
void convert_k(const float* inp, const float* hcur,
               const float* Wt_w, const float* Tr_w, const float* Wa_w,
               const float* Hw_w, const float* Eh_w, const float* Ei_w,
               _Float16* inpH, _Float16* hcH, _Float16* WtH, _Float16* TrH,
               _Float16* WaH, _Float16* HwH, _Float16* EhH, _Float16* EiH,
               int* colcnt)
{
  if (blockIdx.z == 0 && blockIdx.x == 0) {
    for (int k = threadIdx.x; k < 1024; k += 256) colcnt[k] = 0;
  }
  const float* src; _Float16* dh; int n4;
  switch (blockIdx.z) {
    case 0: src = inp;  dh = inpH; n4 = NEL / 4;           break;
    case 1: src = hcur; dh = hcH;  n4 = NEL / 4;           break;
    case 2: src = Wt_w; dh = WtH;  n4 = (1024 * 2048) / 4; break;
    case 3: src = Tr_w; dh = TrH;  n4 = (1024 * 1024) / 4; break;
    case 4: src = Wa_w; dh = WaH;  n4 = (1024 * 2048) / 4; break;
    case 5: src = Hw_w; dh = HwH;  n4 = (1024 * 2048) / 4; break;
    case 6: src = Eh_w; dh = EhH;  n4 = (1024 * 2048) / 4; break;
    default:src = Ei_w; dh = EiH;  n4 = (1024 * 1024) / 4; break;
  }
  for (int i = blockIdx.x * 256 + threadIdx.x; i < n4; i += gridDim.x * 256) {
    const f32x4 v = ((const f32x4*)src)[i];
    half4 h;
#pragma unroll
    for (int j = 0; j < 4; ++j) h[j] = (_Float16)v[j];
    ((half4*)dh)[i] = h;
  }
}

extern "C" void kernel_launch(void* const* d_in, const int* in_sizes, int n_in,
                              void* d_out, int out_size, void* d_ws, size_t ws_size,
                              hipStream_t stream)
{
  const float* inp  = (const float*)d_in[0];
  const float* hcur = (const float*)d_in[1];
  const float* ec   = (const float*)d_in[2];
  const float* tc   = (const float*)d_in[3];
  const float* Wt_w = (const float*)d_in[4];
  const float* Wt_b = (const float*)d_in[5];
  const float* Wa_w = (const float*)d_in[6];
  const float* Wa_b = (const float*)d_in[7];
  const float* Eh_w = (const float*)d_in[8];
  const float* Eh_b = (const float*)d_in[9];
  const float* Hw_w = (const float*)d_in[10];
  const float* Hw_b = (const float*)d_in[11];
  const float* Tr_w = (const float*)d_in[12];
  const float* Tr_b = (const float*)d_in[13];
  const float* Ei_w = (const float*)d_in[14];
  const float* Ei_b = (const float*)d_in[15];

  float* out_h  = (float*)d_out;
  float* out_ex = out_h + NEL;
  float* out_tm = out_ex + NEL;

  char* wsb = (char*)d_ws;
  _Float16* ws_ut  = (_Float16*)(wsb);
  _Float16* ws_ra  = (_Float16*)(wsb + (8u  << 20));
  _Float16* ws_ab  = (_Float16*)(wsb + (16u << 20));
  _Float16* ws_ei  = (_Float16*)(wsb + (24u << 20));
  _Float16* ws_hup = (_Float16*)(wsb + (32u << 20));
  _Float16* ws_hw  = (_Float16*)(wsb + (40u << 20));
  _Float16* inpH   = (_Float16*)(wsb + (48u << 20));
  _Float16* hcH    = (_Float16*)(wsb + (56u << 20));
  _Float16* WtH    = (_Float16*)(wsb + (64u << 20));
  _Float16* TrH    = (_Float16*)(wsb + (68u << 20));
  _Float16* WaH    = (_Float16*)(wsb + (70u << 20));
  _Float16* HwH    = (_Float16*)(wsb + (74u << 20));
  _Float16* EhH    = (_Float16*)(wsb + (78u << 20));
  _Float16* EiH    = (_Float16*)(wsb + (82u << 20));
  int*      d_ccnt = (int*)(wsb + (84u << 20));
  int*      d_clst = (int*)(wsb + (84u << 20) + 4096);   // 1024*512*4B = 2MB

  // Phase 0: f32 -> f16 planes (+ col-counter reset)
  convert_k<<<dim3(512, 1, 8), 256, 0, stream>>>(
      inp, hcur, Wt_w, Tr_w, Wa_w, Hw_w, Eh_w, Ei_w,
      inpH, hcH, WtH, TrH, WaH, HwH, EhH, EiH, d_ccnt);

  // Phase 1: 5 GEMMs in one 256-block 8-phase dispatch
  qurnn_gemm256<<<dim3(256), 512, 0, stream>>>(
      inpH, hcH, WtH, Wt_b, WaH, Wa_b, HwH, Hw_b, TrH, Tr_b, EiH, Ei_b,
      ws_ut, ws_ab, ws_hw, ws_ra, ws_ei);

  // Phase 2: elementwise cell update + per-column boundary flagging
  qurnn_cell<<<dim3(4096), 256, 0, stream>>>(
      (const f32x4*)tc, (const f32x4*)ec, (const f32x4*)hcur,
      (const half4*)ws_ut, (const half4*)ws_ra, (const half4*)ws_ab,
      (const half4*)ws_ei, (f32x4*)out_ex, (f32x4*)out_tm, (half4*)ws_hup,
      d_ccnt, d_clst);

  // Phase 3: exact recompute per column (weights LDS-cached)
  qurnn_fixup<<<dim3(1024), 256, 0, stream>>>(
      d_ccnt, d_clst, inp, hcur, Tr_w, Tr_b, Wt_w, Wt_b,
      ws_ei, ws_ab, tc, ec, out_tm, out_ex, ws_hup);

  // Phase 4: Eh GEMM on [inp | h_up] + fused h_next epilogue (128^2 proven)
  qurnn_eh<<<dim3(256), 256, 0, stream>>>(
      inpH, ws_hup, EhH, Eh_b, ws_hw, hcur, out_h);
}

// Round 11
// 193.387 us; speedup vs baseline: 1.2103x; 1.2103x over previous
//
#include <hip/hip_runtime.h>
#include <math.h>

// QURNN cell, MI355X gfx950, f32 I/O. B=4096, D_IN=D_H=1024.
//
// Round 11: REVERT GEMM to round-8 proven structure (128x128, BK=64,
// involution swizzle, z-major dispatch, 0 bank conflicts, 83.7us) after two
// failed 8-phase ports (104/111us — 1 block/CU kills barrier-overlap).
// Kept from round 10: all gemm5 outputs f16 (ut/ratio f16 saves 32MB of
// traffic; DELTA 4e-3 covers storage error), COLCAP 512.
//
// Dispatches: convert -> gemm5 (z=Wt,Wa,Hw,Tr,Ei) -> cell -> fixup -> eh
//
// ws: ut f16[0,8) ra f16[8,16) ab f16[16,24) ei f16[24,32) hup f16[32,40)
//  hw f16[40,48) inpH[48,56) hcH[56,64) WtH[64,68) TrH[68,70) WaH[70,74)
//  HwH[74,78) EhH[78,82) EiH[82,84) colcnt[84M,+4K) collist[+4K,+2M)

typedef __attribute__((ext_vector_type(4))) float f32x4;
typedef __attribute__((ext_vector_type(8))) _Float16 half8;
typedef __attribute__((ext_vector_type(4))) _Float16 half4;

#define NEL (4096 * 1024)
#define DELTA 4.0e-3f
#define COLCAP 512

__device__ __forceinline__ float sigm(float x) { return 1.0f / (1.0f + expf(-x)); }

__device__ __forceinline__ void gload16(const void* g, void* l) {
  __builtin_amdgcn_global_load_lds(
      (const __attribute__((address_space(1))) void*)g,
      (__attribute__((address_space(3))) void*)l, 16, 0, 0);
}

// OP: 1 tanh->f16, 2 sigmoid->f16, 3 h_next epilogue->f32
template <int OP>
__device__ __forceinline__ void gemm_body(
    _Float16* sm, const int brow, const int bcol,
    const _Float16* A1h, const _Float16* A2h,
    const _Float16* Wh, const float* bias, const int K,
    float* outF, _Float16* outH, const _Float16* hw_p, const float* hc_p)
{
  _Float16* As = sm;            // [128][64] f16, 16KB
  _Float16* Bs = sm + 8192;
  const int tid = threadIdx.x;
  const int lane = tid & 63;
  const int w = tid >> 6;
  const int wr = w >> 1, wc = w & 1;       // 2x2 waves, 64x64 each
  const int lr = lane & 15, lq = lane >> 4;

  f32x4 acc[4][4] = {};

  for (int k0 = 0; k0 < K; k0 += 64) {
    const _Float16* Ah = (k0 < 1024) ? A1h : A2h;
    const int kk = k0 & 1023;
    __syncthreads();
#pragma unroll
    for (int i = 0; i < 4; ++i) {
      const int c_lin = i * 256 + tid;      // 1024 chunks of 16B per tile
      const int row = c_lin >> 3;           // 0..127
      const int c = c_lin & 7;              // linear LDS chunk
      const int src = (c ^ (row & 7)) * 8;  // involution: swizzled source
      gload16(Ah + (size_t)(brow + row) * 1024 + kk + src, &As[row * 64 + c * 8]);
      gload16(Wh + (size_t)(bcol + row) * K + k0 + src,    &Bs[row * 64 + c * 8]);
    }
    __syncthreads();

#pragma unroll
    for (int h = 0; h < 2; ++h) {
      half8 a[4], b[4];
#pragma unroll
      for (int m = 0; m < 4; ++m) {
        const int row = wr * 64 + m * 16 + lr;
        const int ch = (lq + 4 * h) ^ (row & 7);   // same involution on read
        a[m] = *(const half8*)&As[row * 64 + ch * 8];
      }
#pragma unroll
      for (int n = 0; n < 4; ++n) {
        const int row = wc * 64 + n * 16 + lr;
        const int ch = (lq + 4 * h) ^ (row & 7);
        b[n] = *(const half8*)&Bs[row * 64 + ch * 8];
      }
#pragma unroll
      for (int m = 0; m < 4; ++m)
#pragma unroll
        for (int n = 0; n < 4; ++n)
          acc[m][n] = __builtin_amdgcn_mfma_f32_16x16x32_f16(a[m], b[n], acc[m][n], 0, 0, 0);
    }
  }

  float bv[4];
#pragma unroll
  for (int n = 0; n < 4; ++n) bv[n] = bias[bcol + wc * 64 + n * 16 + lr];

#pragma unroll
  for (int m = 0; m < 4; ++m)
#pragma unroll
    for (int n = 0; n < 4; ++n) {
      const int col = bcol + wc * 64 + n * 16 + lr;
#pragma unroll
      for (int j = 0; j < 4; ++j) {
        const int rowg = brow + wr * 64 + m * 16 + lq * 4 + j;
        const size_t idx = (size_t)rowg * 1024 + col;
        const float v = acc[m][n][j] + bv[n];
        if (OP == 1)      outH[idx] = (_Float16)tanhf(v);
        else if (OP == 2) outH[idx] = (_Float16)sigm(v);
        else {
          const float hs = tanhf(v);
          const float hwv = (float)hw_p[idx];
          const float hcv = hc_p[idx];
          outF[idx] = tanhf((1.0f - hwv) * hcv + hwv * hs);
        }
      }
    }
}

// z: 0=Wt(tanh->ut f16) 1=Wa(sig->ab f16) 2=Hw(sig->hw f16)
//    3=Tr(sig->ra f16)  4=Ei(sig->ei f16)
__global__ __launch_bounds__(256, 3)
void qurnn_gemm5(const _Float16* inpH, const _Float16* hcH,
                 const _Float16* WtH, const float* Wt_b,
                 const _Float16* WaH, const float* Wa_b,
                 const _Float16* HwH, const float* Hw_b,
                 const _Float16* TrH, const float* Tr_b,
                 const _Float16* EiH, const float* Ei_b,
                 _Float16* ws_ut, _Float16* ws_ab, _Float16* ws_hw,
                 _Float16* ws_ra, _Float16* ws_ei)
{
  __shared__ __align__(16) _Float16 sm[2 * 8192];   // 32KB
  const int brow = (blockIdx.x & 31) * 128;         // row-fastest: panel reuse
  const int bcol = (blockIdx.x >> 5) * 128;
  switch (blockIdx.z) {
    case 0: gemm_body<1>(sm, brow, bcol, inpH, hcH, WtH, Wt_b, 2048, nullptr, ws_ut, nullptr, nullptr); break;
    case 1: gemm_body<2>(sm, brow, bcol, inpH, hcH, WaH, Wa_b, 2048, nullptr, ws_ab, nullptr, nullptr); break;
    case 2: gemm_body<2>(sm, brow, bcol, inpH, hcH, HwH, Hw_b, 2048, nullptr, ws_hw, nullptr, nullptr); break;
    case 3: gemm_body<2>(sm, brow, bcol, inpH, nullptr, TrH, Tr_b, 1024, nullptr, ws_ra, nullptr, nullptr); break;
    default:gemm_body<2>(sm, brow, bcol, inpH, nullptr, EiH, Ei_b, 1024, nullptr, ws_ei, nullptr, nullptr); break;
  }
}

__global__ __launch_bounds__(256, 3)
void qurnn_eh(const _Float16* inpH, const _Float16* hup,
              const _Float16* EhH, const float* Eh_b,
              const _Float16* hw, const float* hcur, float* out_h)
{
  __shared__ __align__(16) _Float16 sm[2 * 8192];
  const int brow = (blockIdx.x & 31) * 128;
  const int bcol = (blockIdx.x >> 5) * 128;
  gemm_body<3>(sm, brow, bcol, inpH, hup, EhH, Eh_b, 2048,
               out_h, nullptr, hw, hcur);
}

__global__ __launch_bounds__(256)
void qurnn_cell(const f32x4* tc, const f32x4* ec, const f32x4* hc,
                const half4* ut, const half4* ra, const half4* ab,
                const half4* ei, f32x4* out_ex, f32x4* out_tm, half4* hup,
                int* colcnt, int* collist)
{
  const int i = blockIdx.x * 256 + threadIdx.x;   // exact: 4096 blocks
  const f32x4 tcv = tc[i], ecv = ec[i], hcv = hc[i];
  const half4 utv = ut[i], rav = ra[i], abv = ab[i], eiv = ei[i];
  f32x4 to, eo; half4 ho;
#pragma unroll
  for (int j = 0; j < 4; ++j) {
    const float t = (float)rav[j] * fmaxf(tcv[j] + (float)utv[j], 0.0f) - 1.0f;
    const bool leap = (t <= 0.0f);
    to[j] = leap ? 0.0f : t;
    eo[j] = (leap ? 0.0f : ecv[j] + (float)eiv[j]) + (float)abv[j];
    ho[j] = (_Float16)(leap ? hcv[j] * ecv[j] : 0.0f);
    if (fabsf(t) < DELTA) {                  // leap uncertain -> col bucket
      const int e = i * 4 + j;
      const int col = e & 1023;
      const int p = atomicAdd(&colcnt[col], 1);
      if (p < COLCAP) collist[col * COLCAP + p] = e >> 10;  // row
    }
  }
  out_tm[i] = to;
  out_ex[i] = eo;
  hup[i] = ho;
}

// Exact f32 recompute for flagged elements; one block per column, weight
// rows cached in LDS, 4 waves sweep the column's flagged rows.
__global__ __launch_bounds__(256)
void qurnn_fixup(const int* colcnt, const int* collist,
                 const float* inp, const float* hcur,
                 const float* Tr_w, const float* Tr_b,
                 const float* Wt_w, const float* Wt_b,
                 const _Float16* ei, const _Float16* ab,
                 const float* tc, const float* ec,
                 float* out_tm, float* out_ex, _Float16* hup)
{
  const int col = blockIdx.x;                 // 1024 blocks
  const int n_c = min(colcnt[col], COLCAP);
  if (n_c == 0) return;
  __shared__ float wTr[1024];
  __shared__ float wWt[2048];
  const int tid = threadIdx.x;
  for (int k = tid; k < 1024; k += 256) wTr[k] = Tr_w[(size_t)col * 1024 + k];
  for (int k = tid; k < 2048; k += 256) wWt[k] = Wt_w[(size_t)col * 2048 + k];
  __syncthreads();

  const int wid = tid >> 6, lane = tid & 63;
  for (int e = wid; e < n_c; e += 4) {
    const int row = collist[col * COLCAP + e];
    const int idx = row * 1024 + col;
    const f32x4* irow = (const f32x4*)(inp  + (size_t)row * 1024);
    const f32x4* hrow = (const f32x4*)(hcur + (size_t)row * 1024);
    float dTr = 0.0f, dWt = 0.0f;
#pragma unroll
    for (int k = 0; k < 4; ++k) {
      const int q = k * 64 + lane;
      const f32x4 a = irow[q], h = hrow[q];
      const f32x4 w1 = *(const f32x4*)&wTr[q * 4];
      const f32x4 w2 = *(const f32x4*)&wWt[q * 4];
      const f32x4 w3 = *(const f32x4*)&wWt[1024 + q * 4];
#pragma unroll
      for (int j = 0; j < 4; ++j) {
        dTr = fmaf(a[j], w1[j], dTr);
        dWt = fmaf(a[j], w2[j], dWt);
        dWt = fmaf(h[j], w3[j], dWt);
      }
    }
#pragma unroll
    for (int s = 32; s; s >>= 1) {
      dTr += __shfl_xor(dTr, s);
      dWt += __shfl_xor(dWt, s);
    }
    if (lane == 0) {
      const float ratio = sigm(dTr + Tr_b[col]);
      const float utv = tanhf(dWt + Wt_b[col]);
      const float t = ratio * fmaxf(tc[idx] + utv, 0.0f) - 1.0f;
      const bool leap = (t <= 0.0f);
      out_tm[idx] = leap ? 0.0f : t;
      out_ex[idx] = (leap ? 0.0f : ec[idx] + (float)ei[idx]) + (float)ab[idx];
      hup[idx] = (_Float16)(leap ? hcur[idx] * ec[idx] : 0.0f);
    }
  }
}

// f32 -> f16 planes; z=0 block 0 also zeroes the per-col counters.
__global__ __launch_bounds__(256)
void convert_k(const float* inp, const float* hcur,
               const float* Wt_w, const float* Tr_w, const float* Wa_w,
               const float* Hw_w, const float* Eh_w, const float* Ei_w,
               _Float16* inpH, _Float16* hcH, _Float16* WtH, _Float16* TrH,
               _Float16* WaH, _Float16* HwH, _Float16* EhH, _Float16* EiH,
               int* colcnt)
{
  if (blockIdx.z == 0 && blockIdx.x == 0) {
    for (int k = threadIdx.x; k < 1024; k += 256) colcnt[k] = 0;
  }
  const float* src; _Float16* dh; int n4;
  switch (blockIdx.z) {
    case 0: src = inp;  dh = inpH; n4 = NEL / 4;           break;
    case 1: src = hcur; dh = hcH;  n4 = NEL / 4;           break;
    case 2: src = Wt_w; dh = WtH;  n4 = (1024 * 2048) / 4; break;
    case 3: src = Tr_w; dh = TrH;  n4 = (1024 * 1024) / 4; break;
    case 4: src = Wa_w; dh = WaH;  n4 = (1024 * 2048) / 4; break;
    case 5: src = Hw_w; dh = HwH;  n4 = (1024 * 2048) / 4; break;
    case 6: src = Eh_w; dh = EhH;  n4 = (1024 * 2048) / 4; break;
    default:src = Ei_w; dh = EiH;  n4 = (1024 * 1024) / 4; break;
  }
  for (int i = blockIdx.x * 256 + threadIdx.x; i < n4; i += gridDim.x * 256) {
    const f32x4 v = ((const f32x4*)src)[i];
    half4 h;
#pragma unroll
    for (int j = 0; j < 4; ++j) h[j] = (_Float16)v[j];
    ((half4*)dh)[i] = h;
  }
}

extern "C" void kernel_launch(void* const* d_in, const int* in_sizes, int n_in,
                              void* d_out, int out_size, void* d_ws, size_t ws_size,
                              hipStream_t stream)
{
  const float* inp  = (const float*)d_in[0];
  const float* hcur = (const float*)d_in[1];
  const float* ec   = (const float*)d_in[2];
  const float* tc   = (const float*)d_in[3];
  const float* Wt_w = (const float*)d_in[4];
  const float* Wt_b = (const float*)d_in[5];
  const float* Wa_w = (const float*)d_in[6];
  const float* Wa_b = (const float*)d_in[7];
  const float* Eh_w = (const float*)d_in[8];
  const float* Eh_b = (const float*)d_in[9];
  const float* Hw_w = (const float*)d_in[10];
  const float* Hw_b = (const float*)d_in[11];
  const float* Tr_w = (const float*)d_in[12];
  const float* Tr_b = (const float*)d_in[13];
  const float* Ei_w = (const float*)d_in[14];
  const float* Ei_b = (const float*)d_in[15];

  float* out_h  = (float*)d_out;
  float* out_ex = out_h + NEL;
  float* out_tm = out_ex + NEL;

  char* wsb = (char*)d_ws;
  _Float16* ws_ut  = (_Float16*)(wsb);
  _Float16* ws_ra  = (_Float16*)(wsb + (8u  << 20));
  _Float16* ws_ab  = (_Float16*)(wsb + (16u << 20));
  _Float16* ws_ei  = (_Float16*)(wsb + (24u << 20));
  _Float16* ws_hup = (_Float16*)(wsb + (32u << 20));
  _Float16* ws_hw  = (_Float16*)(wsb + (40u << 20));
  _Float16* inpH   = (_Float16*)(wsb + (48u << 20));
  _Float16* hcH    = (_Float16*)(wsb + (56u << 20));
  _Float16* WtH    = (_Float16*)(wsb + (64u << 20));
  _Float16* TrH    = (_Float16*)(wsb + (68u << 20));
  _Float16* WaH    = (_Float16*)(wsb + (70u << 20));
  _Float16* HwH    = (_Float16*)(wsb + (74u << 20));
  _Float16* EhH    = (_Float16*)(wsb + (78u << 20));
  _Float16* EiH    = (_Float16*)(wsb + (82u << 20));
  int*      d_ccnt = (int*)(wsb + (84u << 20));
  int*      d_clst = (int*)(wsb + (84u << 20) + 4096);   // 2MB

  // Phase 0: f32 -> f16 planes (+ col-counter reset)
  convert_k<<<dim3(512, 1, 8), 256, 0, stream>>>(
      inp, hcur, Wt_w, Tr_w, Wa_w, Hw_w, Eh_w, Ei_w,
      inpH, hcH, WtH, TrH, WaH, HwH, EhH, EiH, d_ccnt);

  // Phase 1: 5 GEMMs, z-major (proven L2-friendly layout)
  qurnn_gemm5<<<dim3(256, 1, 5), 256, 0, stream>>>(
      inpH, hcH, WtH, Wt_b, WaH, Wa_b, HwH, Hw_b, TrH, Tr_b, EiH, Ei_b,
      ws_ut, ws_ab, ws_hw, ws_ra, ws_ei);

  // Phase 2: elementwise cell update + per-column boundary flagging
  qurnn_cell<<<dim3(4096), 256, 0, stream>>>(
      (const f32x4*)tc, (const f32x4*)ec, (const f32x4*)hcur,
      (const half4*)ws_ut, (const half4*)ws_ra, (const half4*)ws_ab,
      (const half4*)ws_ei, (f32x4*)out_ex, (f32x4*)out_tm, (half4*)ws_hup,
      d_ccnt, d_clst);

  // Phase 3: exact recompute per column (weights LDS-cached)
  qurnn_fixup<<<dim3(1024), 256, 0, stream>>>(
      d_ccnt, d_clst, inp, hcur, Tr_w, Tr_b, Wt_w, Wt_b,
      ws_ei, ws_ab, tc, ec, out_tm, out_ex, ws_hup);

  // Phase 4: Eh GEMM on [inp | h_up] + fused h_next epilogue
  qurnn_eh<<<dim3(256), 256, 0, stream>>>(
      inpH, ws_hup, EhH, Eh_b, ws_hw, hcur, out_h);
}

// Round 12
// 187.499 us; speedup vs baseline: 1.2483x; 1.0314x over previous
//
#include <hip/hip_runtime.h>
#include <math.h>

// QURNN cell, MI355X gfx950, f32 I/O. B=4096, D_IN=D_H=1024.
//
// Round 12: GEMM structure frozen (round-8/11 proven: 128x128, BK=64,
// involution swizzle, z-major, 0 bank conflicts, ~833 TF = structural
// ceiling of the 2-barrier 128^2 family; both 8-phase ports regressed).
// Non-GEMM tail consolidation:
//  - convert: flat balanced 1D grid over concatenated segments (was
//    per-z uniform 512 blocks -> 4x imbalance between segments).
//  - DELTA 4e-3 -> 2.5e-3 (5-sigma of f16 GEMM+storage error on t).
//  - f16 h_cur (hcH) used in cell hup path and eh epilogue (-16MB f32).
//
// Dispatches: convert -> gemm5 (z=Wt,Wa,Hw,Tr,Ei) -> cell -> fixup -> eh

typedef __attribute__((ext_vector_type(4))) float f32x4;
typedef __attribute__((ext_vector_type(8))) _Float16 half8;
typedef __attribute__((ext_vector_type(4))) _Float16 half4;

#define NEL (4096 * 1024)
#define DELTA 2.5e-3f
#define COLCAP 512

__device__ __forceinline__ float sigm(float x) { return 1.0f / (1.0f + expf(-x)); }

__device__ __forceinline__ void gload16(const void* g, void* l) {
  __builtin_amdgcn_global_load_lds(
      (const __attribute__((address_space(1))) void*)g,
      (__attribute__((address_space(3))) void*)l, 16, 0, 0);
}

// OP: 1 tanh->f16, 2 sigmoid->f16, 3 h_next epilogue->f32
template <int OP>
__device__ __forceinline__ void gemm_body(
    _Float16* sm, const int brow, const int bcol,
    const _Float16* A1h, const _Float16* A2h,
    const _Float16* Wh, const float* bias, const int K,
    float* outF, _Float16* outH, const _Float16* hw_p, const _Float16* hc_p)
{
  _Float16* As = sm;            // [128][64] f16, 16KB
  _Float16* Bs = sm + 8192;
  const int tid = threadIdx.x;
  const int lane = tid & 63;
  const int w = tid >> 6;
  const int wr = w >> 1, wc = w & 1;       // 2x2 waves, 64x64 each
  const int lr = lane & 15, lq = lane >> 4;

  f32x4 acc[4][4] = {};

  for (int k0 = 0; k0 < K; k0 += 64) {
    const _Float16* Ah = (k0 < 1024) ? A1h : A2h;
    const int kk = k0 & 1023;
    __syncthreads();
#pragma unroll
    for (int i = 0; i < 4; ++i) {
      const int c_lin = i * 256 + tid;      // 1024 chunks of 16B per tile
      const int row = c_lin >> 3;           // 0..127
      const int c = c_lin & 7;              // linear LDS chunk
      const int src = (c ^ (row & 7)) * 8;  // involution: swizzled source
      gload16(Ah + (size_t)(brow + row) * 1024 + kk + src, &As[row * 64 + c * 8]);
      gload16(Wh + (size_t)(bcol + row) * K + k0 + src,    &Bs[row * 64 + c * 8]);
    }
    __syncthreads();

#pragma unroll
    for (int h = 0; h < 2; ++h) {
      half8 a[4], b[4];
#pragma unroll
      for (int m = 0; m < 4; ++m) {
        const int row = wr * 64 + m * 16 + lr;
        const int ch = (lq + 4 * h) ^ (row & 7);   // same involution on read
        a[m] = *(const half8*)&As[row * 64 + ch * 8];
      }
#pragma unroll
      for (int n = 0; n < 4; ++n) {
        const int row = wc * 64 + n * 16 + lr;
        const int ch = (lq + 4 * h) ^ (row & 7);
        b[n] = *(const half8*)&Bs[row * 64 + ch * 8];
      }
#pragma unroll
      for (int m = 0; m < 4; ++m)
#pragma unroll
        for (int n = 0; n < 4; ++n)
          acc[m][n] = __builtin_amdgcn_mfma_f32_16x16x32_f16(a[m], b[n], acc[m][n], 0, 0, 0);
    }
  }

  float bv[4];
#pragma unroll
  for (int n = 0; n < 4; ++n) bv[n] = bias[bcol + wc * 64 + n * 16 + lr];

#pragma unroll
  for (int m = 0; m < 4; ++m)
#pragma unroll
    for (int n = 0; n < 4; ++n) {
      const int col = bcol + wc * 64 + n * 16 + lr;
#pragma unroll
      for (int j = 0; j < 4; ++j) {
        const int rowg = brow + wr * 64 + m * 16 + lq * 4 + j;
        const size_t idx = (size_t)rowg * 1024 + col;
        const float v = acc[m][n][j] + bv[n];
        if (OP == 1)      outH[idx] = (_Float16)tanhf(v);
        else if (OP == 2) outH[idx] = (_Float16)sigm(v);
        else {
          const float hs = tanhf(v);
          const float hwv = (float)hw_p[idx];
          const float hcv = (float)hc_p[idx];
          outF[idx] = tanhf((1.0f - hwv) * hcv + hwv * hs);
        }
      }
    }
}

// z: 0=Wt(tanh->ut f16) 1=Wa(sig->ab f16) 2=Hw(sig->hw f16)
//    3=Tr(sig->ra f16)  4=Ei(sig->ei f16)
__global__ __launch_bounds__(256, 3)
void qurnn_gemm5(const _Float16* inpH, const _Float16* hcH,
                 const _Float16* WtH, const float* Wt_b,
                 const _Float16* WaH, const float* Wa_b,
                 const _Float16* HwH, const float* Hw_b,
                 const _Float16* TrH, const float* Tr_b,
                 const _Float16* EiH, const float* Ei_b,
                 _Float16* ws_ut, _Float16* ws_ab, _Float16* ws_hw,
                 _Float16* ws_ra, _Float16* ws_ei)
{
  __shared__ __align__(16) _Float16 sm[2 * 8192];   // 32KB
  const int brow = (blockIdx.x & 31) * 128;         // row-fastest: panel reuse
  const int bcol = (blockIdx.x >> 5) * 128;
  switch (blockIdx.z) {
    case 0: gemm_body<1>(sm, brow, bcol, inpH, hcH, WtH, Wt_b, 2048, nullptr, ws_ut, nullptr, nullptr); break;
    case 1: gemm_body<2>(sm, brow, bcol, inpH, hcH, WaH, Wa_b, 2048, nullptr, ws_ab, nullptr, nullptr); break;
    case 2: gemm_body<2>(sm, brow, bcol, inpH, hcH, HwH, Hw_b, 2048, nullptr, ws_hw, nullptr, nullptr); break;
    case 3: gemm_body<2>(sm, brow, bcol, inpH, nullptr, TrH, Tr_b, 1024, nullptr, ws_ra, nullptr, nullptr); break;
    default:gemm_body<2>(sm, brow, bcol, inpH, nullptr, EiH, Ei_b, 1024, nullptr, ws_ei, nullptr, nullptr); break;
  }
}

__global__ __launch_bounds__(256, 3)
void qurnn_eh(const _Float16* inpH, const _Float16* hup,
              const _Float16* EhH, const float* Eh_b,
              const _Float16* hw, const _Float16* hcH, float* out_h)
{
  __shared__ __align__(16) _Float16 sm[2 * 8192];
  const int brow = (blockIdx.x & 31) * 128;
  const int bcol = (blockIdx.x >> 5) * 128;
  gemm_body<3>(sm, brow, bcol, inpH, hup, EhH, Eh_b, 2048,
               out_h, nullptr, hw, hcH);
}

__global__ __launch_bounds__(256)
void qurnn_cell(const f32x4* tc, const f32x4* ec, const half4* hcH,
                const half4* ut, const half4* ra, const half4* ab,
                const half4* ei, f32x4* out_ex, f32x4* out_tm, half4* hup,
                int* colcnt, int* collist)
{
  const int i = blockIdx.x * 256 + threadIdx.x;   // exact: 4096 blocks
  const f32x4 tcv = tc[i], ecv = ec[i];
  const half4 hcv = hcH[i];
  const half4 utv = ut[i], rav = ra[i], abv = ab[i], eiv = ei[i];
  f32x4 to, eo; half4 ho;
#pragma unroll
  for (int j = 0; j < 4; ++j) {
    const float t = (float)rav[j] * fmaxf(tcv[j] + (float)utv[j], 0.0f) - 1.0f;
    const bool leap = (t <= 0.0f);
    to[j] = leap ? 0.0f : t;
    eo[j] = (leap ? 0.0f : ecv[j] + (float)eiv[j]) + (float)abv[j];
    ho[j] = (_Float16)(leap ? (float)hcv[j] * ecv[j] : 0.0f);
    if (fabsf(t) < DELTA) {                  // leap uncertain -> col bucket
      const int e = i * 4 + j;
      const int col = e & 1023;
      const int p = atomicAdd(&colcnt[col], 1);
      if (p < COLCAP) collist[col * COLCAP + p] = e >> 10;  // row
    }
  }
  out_tm[i] = to;
  out_ex[i] = eo;
  hup[i] = ho;
}

// Exact f32 recompute for flagged elements; one block per column, weight
// rows cached in LDS, 4 waves sweep the column's flagged rows.
__global__ __launch_bounds__(256)
void qurnn_fixup(const int* colcnt, const int* collist,
                 const float* inp, const float* hcur,
                 const float* Tr_w, const float* Tr_b,
                 const float* Wt_w, const float* Wt_b,
                 const _Float16* ei, const _Float16* ab,
                 const float* tc, const float* ec,
                 float* out_tm, float* out_ex, _Float16* hup)
{
  const int col = blockIdx.x;                 // 1024 blocks
  const int n_c = min(colcnt[col], COLCAP);
  if (n_c == 0) return;
  __shared__ float wTr[1024];
  __shared__ float wWt[2048];
  const int tid = threadIdx.x;
  for (int k = tid; k < 1024; k += 256) wTr[k] = Tr_w[(size_t)col * 1024 + k];
  for (int k = tid; k < 2048; k += 256) wWt[k] = Wt_w[(size_t)col * 2048 + k];
  __syncthreads();

  const int wid = tid >> 6, lane = tid & 63;
  for (int e = wid; e < n_c; e += 4) {
    const int row = collist[col * COLCAP + e];
    const int idx = row * 1024 + col;
    const f32x4* irow = (const f32x4*)(inp  + (size_t)row * 1024);
    const f32x4* hrow = (const f32x4*)(hcur + (size_t)row * 1024);
    float dTr = 0.0f, dWt = 0.0f;
#pragma unroll
    for (int k = 0; k < 4; ++k) {
      const int q = k * 64 + lane;
      const f32x4 a = irow[q], h = hrow[q];
      const f32x4 w1 = *(const f32x4*)&wTr[q * 4];
      const f32x4 w2 = *(const f32x4*)&wWt[q * 4];
      const f32x4 w3 = *(const f32x4*)&wWt[1024 + q * 4];
#pragma unroll
      for (int j = 0; j < 4; ++j) {
        dTr = fmaf(a[j], w1[j], dTr);
        dWt = fmaf(a[j], w2[j], dWt);
        dWt = fmaf(h[j], w3[j], dWt);
      }
    }
#pragma unroll
    for (int s = 32; s; s >>= 1) {
      dTr += __shfl_xor(dTr, s);
      dWt += __shfl_xor(dWt, s);
    }
    if (lane == 0) {
      const float ratio = sigm(dTr + Tr_b[col]);
      const float utv = tanhf(dWt + Wt_b[col]);
      const float t = ratio * fmaxf(tc[idx] + utv, 0.0f) - 1.0f;
      const bool leap = (t <= 0.0f);
      out_tm[idx] = leap ? 0.0f : t;
      out_ex[idx] = (leap ? 0.0f : ec[idx] + (float)ei[idx]) + (float)ab[idx];
      hup[idx] = (_Float16)(leap ? hcur[idx] * ec[idx] : 0.0f);
    }
  }
}

// Flat, load-balanced f32->f16 conversion over all 8 segments.
// Segment boundaries in f32x4 units (prefix sums).
#define SEG0 1048576u   // inp
#define SEG1 2097152u   // + hcur
#define SEG2 2621440u   // + Wt (512K)
#define SEG3 2883584u   // + Tr (256K)
#define SEG4 3407872u   // + Wa
#define SEG5 3932160u   // + Hw
#define SEG6 4456448u   // + Eh
#define SEG7 4718592u   // + Ei (total)

__global__ __launch_bounds__(256)
void convert_k(const float* inp, const float* hcur,
               const float* Wt_w, const float* Tr_w, const float* Wa_w,
               const float* Hw_w, const float* Eh_w, const float* Ei_w,
               _Float16* inpH, _Float16* hcH, _Float16* WtH, _Float16* TrH,
               _Float16* WaH, _Float16* HwH, _Float16* EhH, _Float16* EiH,
               int* colcnt)
{
  if (blockIdx.x == 0) {
    for (int k = threadIdx.x; k < 1024; k += 256) colcnt[k] = 0;
  }
  const unsigned stride = gridDim.x * 256;
  for (unsigned i = blockIdx.x * 256 + threadIdx.x; i < SEG7; i += stride) {
    const float* src; _Float16* dh; unsigned off;
    if (i < SEG0)      { src = inp;  dh = inpH; off = 0; }
    else if (i < SEG1) { src = hcur; dh = hcH;  off = SEG0; }
    else if (i < SEG2) { src = Wt_w; dh = WtH;  off = SEG1; }
    else if (i < SEG3) { src = Tr_w; dh = TrH;  off = SEG2; }
    else if (i < SEG4) { src = Wa_w; dh = WaH;  off = SEG3; }
    else if (i < SEG5) { src = Hw_w; dh = HwH;  off = SEG4; }
    else if (i < SEG6) { src = Eh_w; dh = EhH;  off = SEG5; }
    else               { src = Ei_w; dh = EiH;  off = SEG6; }
    const unsigned k = i - off;
    const f32x4 v = ((const f32x4*)src)[k];
    half4 h;
#pragma unroll
    for (int j = 0; j < 4; ++j) h[j] = (_Float16)v[j];
    ((half4*)dh)[k] = h;
  }
}

extern "C" void kernel_launch(void* const* d_in, const int* in_sizes, int n_in,
                              void* d_out, int out_size, void* d_ws, size_t ws_size,
                              hipStream_t stream)
{
  const float* inp  = (const float*)d_in[0];
  const float* hcur = (const float*)d_in[1];
  const float* ec   = (const float*)d_in[2];
  const float* tc   = (const float*)d_in[3];
  const float* Wt_w = (const float*)d_in[4];
  const float* Wt_b = (const float*)d_in[5];
  const float* Wa_w = (const float*)d_in[6];
  const float* Wa_b = (const float*)d_in[7];
  const float* Eh_w = (const float*)d_in[8];
  const float* Eh_b = (const float*)d_in[9];
  const float* Hw_w = (const float*)d_in[10];
  const float* Hw_b = (const float*)d_in[11];
  const float* Tr_w = (const float*)d_in[12];
  const float* Tr_b = (const float*)d_in[13];
  const float* Ei_w = (const float*)d_in[14];
  const float* Ei_b = (const float*)d_in[15];

  float* out_h  = (float*)d_out;
  float* out_ex = out_h + NEL;
  float* out_tm = out_ex + NEL;

  char* wsb = (char*)d_ws;
  _Float16* ws_ut  = (_Float16*)(wsb);
  _Float16* ws_ra  = (_Float16*)(wsb + (8u  << 20));
  _Float16* ws_ab  = (_Float16*)(wsb + (16u << 20));
  _Float16* ws_ei  = (_Float16*)(wsb + (24u << 20));
  _Float16* ws_hup = (_Float16*)(wsb + (32u << 20));
  _Float16* ws_hw  = (_Float16*)(wsb + (40u << 20));
  _Float16* inpH   = (_Float16*)(wsb + (48u << 20));
  _Float16* hcH    = (_Float16*)(wsb + (56u << 20));
  _Float16* WtH    = (_Float16*)(wsb + (64u << 20));
  _Float16* TrH    = (_Float16*)(wsb + (68u << 20));
  _Float16* WaH    = (_Float16*)(wsb + (70u << 20));
  _Float16* HwH    = (_Float16*)(wsb + (74u << 20));
  _Float16* EhH    = (_Float16*)(wsb + (78u << 20));
  _Float16* EiH    = (_Float16*)(wsb + (82u << 20));
  int*      d_ccnt = (int*)(wsb + (84u << 20));
  int*      d_clst = (int*)(wsb + (84u << 20) + 4096);   // 2MB

  // Phase 0: flat balanced f32 -> f16 planes (+ col-counter reset)
  convert_k<<<dim3(2048), 256, 0, stream>>>(
      inp, hcur, Wt_w, Tr_w, Wa_w, Hw_w, Eh_w, Ei_w,
      inpH, hcH, WtH, TrH, WaH, HwH, EhH, EiH, d_ccnt);

  // Phase 1: 5 GEMMs, z-major (proven L2-friendly layout)
  qurnn_gemm5<<<dim3(256, 1, 5), 256, 0, stream>>>(
      inpH, hcH, WtH, Wt_b, WaH, Wa_b, HwH, Hw_b, TrH, Tr_b, EiH, Ei_b,
      ws_ut, ws_ab, ws_hw, ws_ra, ws_ei);

  // Phase 2: elementwise cell update + per-column boundary flagging
  qurnn_cell<<<dim3(4096), 256, 0, stream>>>(
      (const f32x4*)tc, (const f32x4*)ec, (const half4*)hcH,
      (const half4*)ws_ut, (const half4*)ws_ra, (const half4*)ws_ab,
      (const half4*)ws_ei, (f32x4*)out_ex, (f32x4*)out_tm, (half4*)ws_hup,
      d_ccnt, d_clst);

  // Phase 3: exact recompute per column (weights LDS-cached)
  qurnn_fixup<<<dim3(1024), 256, 0, stream>>>(
      d_ccnt, d_clst, inp, hcur, Tr_w, Tr_b, Wt_w, Wt_b,
      ws_ei, ws_ab, tc, ec, out_tm, out_ex, ws_hup);

  // Phase 4: Eh GEMM on [inp | h_up] + fused h_next epilogue
  qurnn_eh<<<dim3(256), 256, 0, stream>>>(
      inpH, ws_hup, EhH, Eh_b, ws_hw, hcH, out_h);
}